// Round 11
// baseline (294.753 us; speedup 1.0000x reference)
//
#include <hip/hip_runtime.h>
#include <hip/hip_bf16.h>
#include <math.h>

typedef float f32x4 __attribute__((ext_vector_type(4)));
typedef _Float16 f16x8 __attribute__((ext_vector_type(8)));
typedef _Float16 f16x4 __attribute__((ext_vector_type(4)));

#define TT 1024
#define DD 1024
#define QS 4096   // mega1 row stride (f16): [qkv 3072 | mv 1024]

typedef __attribute__((address_space(1))) const void gas_void;
typedef __attribute__((address_space(3))) void las_void;
static __device__ __forceinline__ void gl_lds16(const void* g, void* l) {
  __builtin_amdgcn_global_load_lds((gas_void*)g, (las_void*)l, 16, 0, 0);
}

// ============ f16 GEMM: 128x256 tile, 8-phase schedule (m201 port), BK=64, 3-buf ring ============
// A[2048][K] f16, Wt[N][K] f16. C = A·Wt^T (+bias)(+gelu).
// 512 thr, 8 waves 2M x 4N (wave tile 64x64, acc[4][4]). Grid: 16 row-tiles x N/256 cols, XCD-swizzled.
// LDS: 3 bufs x {A 128x64 (16KB) + B 256x64 (32KB)} = 144KB. Swizzle: LDS pos p of row r holds
// K-chunk p^(r&7) (8 chunks of 8 f16/row); staged via pre-swizzled global src, read via XOR (rule 21).
// Per K-tile: 4 phases {8 ds_read (2m x 2n quadrant) | <=2 gl_lds prefetch(t+2) | BAR | lgkm0 | prio1 |
// 8 MFMA | prio0 | BAR}; tile gate = counted vmcnt(6) (t+1's 6 loads stay in flight) + BAR.
// mode: 1 = store f16, 2 = atomicAdd f32 (pre-initialized buffer; bias ignored)
__global__ __launch_bounds__(512) void gemm8(
    const _Float16* __restrict__ A, const _Float16* __restrict__ Wt,
    const float* __restrict__ bias, void* __restrict__ Cv,
    int N, int K, int act, int mode, int nt) {
  __shared__ __align__(16) _Float16 AsB[3 * 8192];    // 3 x 16KB
  __shared__ __align__(16) _Float16 BsB[3 * 16384];   // 3 x 32KB
  const int tid = threadIdx.x;
  const int lane = tid & 63;
  const int wid = tid >> 6;
  const int wrow = wid >> 2, wcol = wid & 3;     // 2M x 4N waves, tile 64x64
  const int g = lane >> 4, l16 = lane & 15;
  const int x7 = l16 & 7;
  const int cpx = gridDim.x >> 3;
  const int wg = (blockIdx.x & 7) * cpx + (blockIdx.x >> 3);
  const int row0 = (wg & 15) * 128;
  const int col0 = (wg >> 4) * 256;
  const int kbeg = blockIdx.y * nt * 64;

  f32x4 acc[4][4];
#pragma unroll
  for (int m = 0; m < 4; ++m)
#pragma unroll
    for (int n = 0; n < 4; ++n) acc[m][n] = (f32x4){0.f, 0.f, 0.f, 0.f};

  // fragment-read offsets (f16 elements)
  int arow[4], brow[4];
#pragma unroll
  for (int m = 0; m < 4; ++m) arow[m] = (wrow * 64 + m * 16 + l16) * 64;
#pragma unroll
  for (int n = 0; n < 4; ++n) brow[n] = (wcol * 64 + n * 16 + l16) * 64;
  const int kof0 = ((0 + g) ^ x7) * 8;
  const int kof1 = ((4 + g) ^ x7) * 8;

  // staging geometry (pre-swizzled global source, linear LDS dest)
  const int rA0 = tid >> 3,          pA0 = tid & 7;
  const int rA1 = (tid + 512) >> 3,  pA1 = tid & 7;
  const _Float16* agp0 = A + (size_t)(row0 + rA0) * K + kbeg + ((pA0 ^ (rA0 & 7)) << 3);
  const _Float16* agp1 = A + (size_t)(row0 + rA1) * K + kbeg + ((pA1 ^ (rA1 & 7)) << 3);
  const int lda0 = tid * 16, lda1 = (tid + 512) * 16;   // bytes
  const _Float16* bgp[4];
  int ldb[4];
#pragma unroll
  for (int j = 0; j < 4; ++j) {
    const int s = tid + 512 * j;
    const int r = s >> 3, p = s & 7;
    bgp[j] = Wt + (size_t)(col0 + r) * K + kbeg + ((p ^ (r & 7)) << 3);
    ldb[j] = s * 16;
  }

#define STAGE_A(FB, T) {                                                        \
    const size_t ko_ = (size_t)(T) * 64;                                        \
    gl_lds16(agp0 + ko_, (char*)AsB + (size_t)(FB) * 16384 + lda0);             \
    gl_lds16(agp1 + ko_, (char*)AsB + (size_t)(FB) * 16384 + lda1); }
#define STAGE_B01(FB, T) {                                                      \
    const size_t ko_ = (size_t)(T) * 64;                                        \
    gl_lds16(bgp[0] + ko_, (char*)BsB + (size_t)(FB) * 32768 + ldb[0]);         \
    gl_lds16(bgp[1] + ko_, (char*)BsB + (size_t)(FB) * 32768 + ldb[1]); }
#define STAGE_B23(FB, T) {                                                      \
    const size_t ko_ = (size_t)(T) * 64;                                        \
    gl_lds16(bgp[2] + ko_, (char*)BsB + (size_t)(FB) * 32768 + ldb[2]);         \
    gl_lds16(bgp[3] + ko_, (char*)BsB + (size_t)(FB) * 32768 + ldb[3]); }

#define MFMA_(a, b, c) c = __builtin_amdgcn_mfma_f32_16x16x32_f16(a, b, c, 0, 0, 0)
#define PHASEBODY(MP, NP, STAGECODE, TAILCODE)                                  \
  {                                                                             \
    const _Float16* Ab = AsB + cb * 8192;                                       \
    const _Float16* Bb = BsB + cb * 16384;                                      \
    f16x8 a00 = *(const f16x8*)(Ab + arow[MP]     + kof0);                      \
    f16x8 a01 = *(const f16x8*)(Ab + arow[MP]     + kof1);                      \
    f16x8 a10 = *(const f16x8*)(Ab + arow[MP + 1] + kof0);                      \
    f16x8 a11 = *(const f16x8*)(Ab + arow[MP + 1] + kof1);                      \
    f16x8 b00 = *(const f16x8*)(Bb + brow[NP]     + kof0);                      \
    f16x8 b01 = *(const f16x8*)(Bb + brow[NP]     + kof1);                      \
    f16x8 b10 = *(const f16x8*)(Bb + brow[NP + 1] + kof0);                      \
    f16x8 b11 = *(const f16x8*)(Bb + brow[NP + 1] + kof1);                      \
    STAGECODE                                                                   \
    __builtin_amdgcn_s_barrier();                                               \
    asm volatile("s_waitcnt lgkmcnt(0)" ::: "memory");                          \
    __builtin_amdgcn_sched_barrier(0);                                          \
    __builtin_amdgcn_s_setprio(1);                                              \
    MFMA_(a00, b00, acc[MP][NP]);                                               \
    MFMA_(a00, b10, acc[MP][NP + 1]);                                           \
    MFMA_(a10, b00, acc[MP + 1][NP]);                                           \
    MFMA_(a10, b10, acc[MP + 1][NP + 1]);                                       \
    MFMA_(a01, b01, acc[MP][NP]);                                               \
    MFMA_(a01, b11, acc[MP][NP + 1]);                                           \
    MFMA_(a11, b01, acc[MP + 1][NP]);                                           \
    MFMA_(a11, b11, acc[MP + 1][NP + 1]);                                       \
    __builtin_amdgcn_s_setprio(0);                                              \
    TAILCODE                                                                    \
    __builtin_amdgcn_s_barrier();                                               \
  }

  // prologue: stage tiles 0,1 into bufs 0,1
  STAGE_A(0, 0); STAGE_B01(0, 0); STAGE_B23(0, 0);
  if (nt > 1) { STAGE_A(1, 1); STAGE_B01(1, 1); STAGE_B23(1, 1); }
  if (nt > 1) asm volatile("s_waitcnt vmcnt(6)" ::: "memory");
  else        asm volatile("s_waitcnt vmcnt(0)" ::: "memory");
  __builtin_amdgcn_s_barrier();
  __builtin_amdgcn_sched_barrier(0);

  int cb = 0;
  for (int t = 0; t < nt; ++t) {
    const int fb = (cb + 2 >= 3) ? cb - 1 : cb + 2;
    const bool pf = (t + 2) < nt;
    __builtin_amdgcn_sched_barrier(0);
    PHASEBODY(0, 0, if (pf) STAGE_A(fb, t + 2);, )
    PHASEBODY(0, 2, if (pf) STAGE_B01(fb, t + 2);, )
    PHASEBODY(2, 0, if (pf) STAGE_B23(fb, t + 2);, )
    PHASEBODY(2, 2, ,
      if (t + 1 < nt) {
        if (pf) asm volatile("s_waitcnt vmcnt(6)" ::: "memory");
        else    asm volatile("s_waitcnt vmcnt(0)" ::: "memory");
      } )
    cb = (cb == 2) ? 0 : cb + 1;
  }
#undef PHASEBODY
#undef MFMA_
#undef STAGE_A
#undef STAGE_B01
#undef STAGE_B23

#pragma unroll
  for (int m = 0; m < 4; ++m) {
#pragma unroll
    for (int n = 0; n < 4; ++n) {
      const int col = col0 + wcol * 64 + n * 16 + l16;
      const float bv = (mode != 2 && bias) ? bias[col] : 0.f;
#pragma unroll
      for (int rg = 0; rg < 4; ++rg) {
        const int row = row0 + wrow * 64 + m * 16 + g * 4 + rg;
        const size_t off = (size_t)row * N + col;
        float v = acc[m][n][rg] + bv;
        if (act == 1) v = 0.5f * v * (1.f + erff(v * 0.70710678118654752f));
        if (mode == 2) atomicAdd(&((float*)Cv)[off], v);
        else ((_Float16*)Cv)[off] = (_Float16)v;
      }
    }
  }
}

// ============ weight transpose+convert: W[K][N] f32 -> WT[N][K] f16 ============
__global__ __launch_bounds__(256) void transT(const float* __restrict__ W,
                                              _Float16* __restrict__ WT, int K, int N) {
  __shared__ float tile[64][65];
  const int n0 = blockIdx.x * 64, k0 = blockIdx.y * 64;
  const int tn = threadIdx.x & 63, tk4 = threadIdx.x >> 6;
#pragma unroll
  for (int it = 0; it < 16; ++it) {
    const int k = k0 + it * 4 + tk4;
    tile[tn][it * 4 + tk4] = W[(size_t)k * N + n0 + tn];
  }
  __syncthreads();
  const int on = threadIdx.x >> 2, ok = threadIdx.x & 3;
  f16x8 a, b;
#pragma unroll
  for (int j = 0; j < 8; ++j) {
    a[j] = (_Float16)tile[on][ok * 16 + j];
    b[j] = (_Float16)tile[on][ok * 16 + 8 + j];
  }
  _Float16* dst = WT + (size_t)(n0 + on) * K + k0 + ok * 16;
  *(f16x8*)dst = a;
  *(f16x8*)(dst + 8) = b;
}

// ============ build WmT [4608][1024]: rows 0..3071 qkv | 3072..4095 mv | 4096..4607 lines ============
__global__ __launch_bounds__(256) void prep_megaT(
    const float* __restrict__ Wqkv, const float* __restrict__ W1w, const float* __restrict__ W2w,
    const float* __restrict__ W1r, const float* __restrict__ W2r, const float* __restrict__ Wmg,
    const float* __restrict__ Wmv, _Float16* __restrict__ WmT) {
  __shared__ float tile[64][65];
  const int n0 = blockIdx.x * 64, k0 = blockIdx.y * 64;
  const int tn = threadIdx.x & 63, tk4 = threadIdx.x >> 6;
#pragma unroll
  for (int it = 0; it < 16; ++it) {
    const int k = k0 + it * 4 + tk4;
    const int n = n0 + tn;
    float v;
    if (n < 3072) v = Wqkv[(size_t)k * 3072 + n];
    else if (n < 4096) v = Wmv[(size_t)k * 1024 + n - 3072];
    else {
      const int c = n - 4096;
      if (c < 64) v = W1w[k * 64 + c];
      else if (c < 128) v = W2w[k * 64 + c - 64];
      else if (c < 192) v = W1r[k * 64 + c - 128];
      else if (c < 256) v = W2r[k * 64 + c - 192];
      else if (c < 272) v = Wmg[k * 16 + c - 256];
      else v = 0.f;
    }
    tile[tn][it * 4 + tk4] = v;
  }
  __syncthreads();
  const int on = threadIdx.x >> 2, ok = threadIdx.x & 3;
  f16x8 a, b;
#pragma unroll
  for (int j = 0; j < 8; ++j) {
    a[j] = (_Float16)tile[on][ok * 16 + j];
    b[j] = (_Float16)tile[on][ok * 16 + 8 + j];
  }
  _Float16* dst = WmT + (size_t)(n0 + on) * 1024 + k0 + ok * 16;
  *(f16x8*)dst = a;
  *(f16x8*)(dst + 8) = b;
}

__global__ void bm_init(const float* __restrict__ bqkv, const float* __restrict__ bmg,
                        const float* __restrict__ bmv, float* __restrict__ bm) {
  const int col = blockIdx.x * 256 + threadIdx.x;
  if (col >= 4608) return;
  float b = 0.f;
  if (col < 3072) b = bqkv[col];
  else if (col < 4096) b = bmv[col - 3072];
  else if (col >= 4096 + 256 && col < 4096 + 272) b = bmg[col - 4096 - 256];
  bm[col] = b;
}

// ============ LayerNorm -> f16 ============
__global__ __launch_bounds__(256) void ln16(const float* __restrict__ in,
    const float* __restrict__ gw, const float* __restrict__ bw, _Float16* __restrict__ out) {
  const int row = blockIdx.x, tid = threadIdx.x;
  const float* x = in + (size_t)row * DD;
  const float4 v = *(const float4*)(x + tid * 4);
  float s = v.x + v.y + v.z + v.w;
  float sq = v.x * v.x + v.y * v.y + v.z * v.z + v.w * v.w;
#pragma unroll
  for (int off = 32; off >= 1; off >>= 1) { s += __shfl_xor(s, off); sq += __shfl_xor(sq, off); }
  __shared__ float red[8];
  const int lane = tid & 63, wv = tid >> 6;
  if (lane == 0) { red[wv] = s; red[4 + wv] = sq; }
  __syncthreads();
  s = red[0] + red[1] + red[2] + red[3];
  sq = red[4] + red[5] + red[6] + red[7];
  const float mean = s * (1.f / 1024.f);
  const float var = sq * (1.f / 1024.f) - mean * mean;
  const float rstd = rsqrtf(var + 1e-5f);
  const float4 g4 = *(const float4*)(gw + tid * 4);
  const float4 b4 = *(const float4*)(bw + tid * 4);
  f16x4 o;
  o[0] = (_Float16)((v.x - mean) * rstd * g4.x + b4.x);
  o[1] = (_Float16)((v.y - mean) * rstd * g4.y + b4.y);
  o[2] = (_Float16)((v.z - mean) * rstd * g4.z + b4.z);
  o[3] = (_Float16)((v.w - mean) * rstd * g4.w + b4.w);
  *(f16x4*)(out + (size_t)row * DD + tid * 4) = o;
}

// ============ MFMA f16 causal flash attention (f16 qkv input, stride QS=4096) ============
static __device__ __forceinline__ int swzA(int row, int k) {
  return row * 64 + ((((k >> 3) ^ row) & 7) << 3) + (k & 7);
}
static __device__ __forceinline__ int swzV(int row, int k) {
  return row * 64 + ((((k >> 3) ^ row ^ (row >> 3)) & 7) << 3) + (k & 7);
}

__global__ __launch_bounds__(256) void attn_mfma(const _Float16* __restrict__ qkv,
                                                 _Float16* __restrict__ seq_out) {
  __shared__ __align__(16) _Float16 Kl[64 * 64];
  __shared__ __align__(16) _Float16 Vt[64 * 64];
  __shared__ __align__(16) _Float16 Pl[4][16 * 64];
  const int tid = threadIdx.x, lane = tid & 63, wq = tid >> 6;
  const int g = lane >> 4, l16 = lane & 15;
  const int qt = blockIdx.x, hh = blockIdx.y, bb = blockIdx.z;
  const int nt = qt + 1;

  f16x8 qf[2];
  {
    const _Float16* qp = qkv + (size_t)(bb * TT + qt * 64 + wq * 16 + l16) * QS + hh * 64;
#pragma unroll
    for (int ks = 0; ks < 2; ++ks) {
      const f16x8 a = *(const f16x8*)(qp + ks * 32 + g * 8);
#pragma unroll
      for (int j = 0; j < 8; ++j) qf[ks][j] = (_Float16)((float)a[j] * 0.125f);
    }
  }

  f32x4 oacc[4];
#pragma unroll
  for (int n = 0; n < 4; ++n) oacc[n] = (f32x4){0.f, 0.f, 0.f, 0.f};
  float m[4] = {-INFINITY, -INFINITY, -INFINITY, -INFINITY};
  float l[4] = {0.f, 0.f, 0.f, 0.f};

  const int skey = tid >> 2, sc4 = tid & 3;

  for (int tt = 0; tt < nt; ++tt) {
    if (tt) __syncthreads();
    {
      const _Float16* kp = qkv + (size_t)(bb * TT + tt * 64 + skey) * QS + hh * 64 + 1024;
      const _Float16* vp = kp + 1024;
#pragma unroll
      for (int ii = 0; ii < 4; ++ii) {
        const int d0 = sc4 * 4 + ii * 16;
        *(f16x4*)(Kl + swzA(skey, d0)) = *(const f16x4*)(kp + d0);
        const f16x4 vv = *(const f16x4*)(vp + d0);
        Vt[swzV(d0 + 0, skey)] = vv[0];
        Vt[swzV(d0 + 1, skey)] = vv[1];
        Vt[swzV(d0 + 2, skey)] = vv[2];
        Vt[swzV(d0 + 3, skey)] = vv[3];
      }
    }
    __syncthreads();
    f32x4 s[4];
#pragma unroll
    for (int n = 0; n < 4; ++n) s[n] = (f32x4){0.f, 0.f, 0.f, 0.f};
#pragma unroll
    for (int ks = 0; ks < 2; ++ks) {
      f16x8 kf[4];
#pragma unroll
      for (int n = 0; n < 4; ++n) kf[n] = *(const f16x8*)(Kl + swzA(n * 16 + l16, ks * 32 + g * 8));
#pragma unroll
      for (int n = 0; n < 4; ++n)
        s[n] = __builtin_amdgcn_mfma_f32_16x16x32_f16(qf[ks], kf[n], s[n], 0, 0, 0);
    }
    if (tt == qt) {
      const int rloc = wq * 16 + g * 4;
#pragma unroll
      for (int n = 0; n < 4; ++n) {
        const int cloc = n * 16 + l16;
#pragma unroll
        for (int reg = 0; reg < 4; ++reg)
          if (cloc > rloc + reg) s[n][reg] = -INFINITY;
      }
    }
    float f[4];
#pragma unroll
    for (int reg = 0; reg < 4; ++reg) {
      float t = fmaxf(fmaxf(s[0][reg], s[1][reg]), fmaxf(s[2][reg], s[3][reg]));
#pragma unroll
      for (int off = 1; off < 16; off <<= 1) t = fmaxf(t, __shfl_xor(t, off));
      const float nm = fmaxf(m[reg], t);
      f[reg] = __expf(m[reg] - nm);
      m[reg] = nm;
    }
    float rs[4] = {0.f, 0.f, 0.f, 0.f};
#pragma unroll
    for (int n = 0; n < 4; ++n) {
#pragma unroll
      for (int reg = 0; reg < 4; ++reg) {
        const float p = __expf(s[n][reg] - m[reg]);
        rs[reg] += p;
        Pl[wq][swzA(g * 4 + reg, n * 16 + l16)] = (_Float16)p;
      }
    }
#pragma unroll
    for (int reg = 0; reg < 4; ++reg) {
      float t = rs[reg];
#pragma unroll
      for (int off = 1; off < 16; off <<= 1) t += __shfl_xor(t, off);
      l[reg] = l[reg] * f[reg] + t;
    }
#pragma unroll
    for (int n = 0; n < 4; ++n)
#pragma unroll
      for (int reg = 0; reg < 4; ++reg) oacc[n][reg] *= f[reg];
#pragma unroll
    for (int ks = 0; ks < 2; ++ks) {
      const f16x8 pa = *(const f16x8*)(Pl[wq] + swzA(l16, ks * 32 + g * 8));
      f16x8 vb[4];
#pragma unroll
      for (int n = 0; n < 4; ++n) vb[n] = *(const f16x8*)(Vt + swzV(n * 16 + l16, ks * 32 + g * 8));
#pragma unroll
      for (int n = 0; n < 4; ++n)
        oacc[n] = __builtin_amdgcn_mfma_f32_16x16x32_f16(pa, vb[n], oacc[n], 0, 0, 0);
    }
  }
#pragma unroll
  for (int n = 0; n < 4; ++n) {
#pragma unroll
    for (int reg = 0; reg < 4; ++reg) {
      const int r = qt * 64 + wq * 16 + g * 4 + reg;
      seq_out[(size_t)(bb * TT + r) * DD + hh * 64 + n * 16 + l16] = (_Float16)(oacc[n][reg] / l[reg]);
    }
  }
}

// ============ exterior products -> Jw, rd, gate (reads lines16 [2048][512] f16) ============
static __device__ __forceinline__ void ext6(const float* a, const float* b, float* L) {
  L[0] = a[0] * b[1] - a[1] * b[0];
  L[1] = a[0] * b[2] - a[2] * b[0];
  L[2] = a[0] * b[3] - a[3] * b[0];
  L[3] = a[1] * b[2] - a[2] * b[1];
  L[4] = a[1] * b[3] - a[3] * b[1];
  L[5] = a[2] * b[3] - a[3] * b[2];
  const float n = sqrtf(L[0]*L[0] + L[1]*L[1] + L[2]*L[2] + L[3]*L[3] + L[4]*L[4] + L[5]*L[5]);
  const float s = 1.f / fmaxf(n, 1e-12f);
#pragma unroll
  for (int i = 0; i < 6; ++i) L[i] *= s;
}

__global__ void lines_post(const _Float16* __restrict__ lines, float* __restrict__ jw,
                           float* __restrict__ rdv, float* __restrict__ gate) {
  const int idx = blockIdx.x * 256 + threadIdx.x;
  const int h = idx & 15;
  const int bt = idx >> 4;
  const int t = bt & 1023;
  const int b = bt >> 10;
  const _Float16* row = lines + (size_t)bt * 512;
  float w1[4] = {0.f, 0.f, 0.f, 0.f}, w2[4], r1[4], r2[4];
  if (t > 0) {
#pragma unroll
    for (int i = 0; i < 4; ++i) w1[i] = (float)row[-512 + h * 4 + i];
  }
#pragma unroll
  for (int i = 0; i < 4; ++i) {
    w2[i] = (float)row[64 + h * 4 + i];
    r1[i] = (float)row[128 + h * 4 + i];
    r2[i] = (float)row[192 + h * 4 + i];
  }
  const float gp = (float)row[256 + h];
  float wl[6], rl[6];
  ext6(w1, w2, wl);
  ext6(r1, r2, rl);
  const size_t o = ((size_t)(b * 16 + h) * 1024 + t) * 6;
  jw[o + 0] =  wl[5]; jw[o + 1] = -wl[4]; jw[o + 2] =  wl[3];
  jw[o + 3] =  wl[2]; jw[o + 4] = -wl[1]; jw[o + 5] =  wl[0];
#pragma unroll
  for (int i = 0; i < 6; ++i) rdv[o + i] = rl[i];
  gate[idx] = 1.f / (1.f + __expf(-gp));
}

// ============ chunk-parallel Gram scan ============
static __device__ __forceinline__ int midx(int i, int j) {
  return (i <= j) ? (i * (13 - i)) / 2 + (j - i) : (j * (13 - j)) / 2 + (i - j);
}

__global__ __launch_bounds__(64) void gram_scan(const float* __restrict__ jwv,
    const float* __restrict__ rdv, const float* __restrict__ decay_logits,
    const float* __restrict__ iter_mix, float* __restrict__ mem_score) {
  const int h = blockIdx.x & 15, b = blockIdx.x >> 4;
  const int lane = threadIdx.x;
  const float decay = 1.f / (1.f + __expf(-decay_logits[h]));
  const float alpha = 1.f / (1.f + __expf(-iter_mix[0]));
  __shared__ float sd[64 * 193];
  const size_t base = (size_t)(b * 16 + h) * 1024 * 6;
  for (int it = 0; it < 96; ++it) {
    const int idx = it * 64 + lane;
    const int t = idx / 6, i = idx - 6 * t;
    const int ld = t >> 4, s = t & 15;
    sd[ld * 193 + s * 6 + i] = jwv[base + idx];
    sd[ld * 193 + 96 + s * 6 + i] = rdv[base + idx];
  }
  __syncthreads();
  const float* seg = sd + lane * 193;

  float C[21];
#pragma unroll
  for (int e = 0; e < 21; ++e) C[e] = 0.f;
  for (int s = 0; s < 16; ++s) {
    float J[6], dJ[6];
#pragma unroll
    for (int i = 0; i < 6; ++i) { J[i] = seg[s * 6 + i]; dJ[i] = decay * J[i]; }
#pragma unroll
    for (int i = 0; i < 6; ++i)
#pragma unroll
      for (int j = i; j < 6; ++j)
        C[midx(i, j)] = decay * C[midx(i, j)] + dJ[i] * J[j];
  }
  const float d2 = decay * decay, d4 = d2 * d2, d8 = d4 * d4;
  float fk = d8 * d8;  // d^16
#pragma unroll
  for (int k = 0; k < 6; ++k) {
    const int off = 1 << k;
#pragma unroll
    for (int e = 0; e < 21; ++e) {
      const float u = __shfl(C[e], lane - off);
      if (lane >= off) C[e] += fk * u;
    }
    fk = fk * fk;
  }
  float M[21];
#pragma unroll
  for (int e = 0; e < 21; ++e) {
    const float u = __shfl(C[e], lane - 1);
    M[e] = (lane >= 1) ? u : 0.f;
  }
  float* msp = mem_score + (size_t)(b * 16 + h) * 1024 + lane * 16;
  for (int s = 0; s < 16; ++s) {
    float J[6], r[6];
#pragma unroll
    for (int i = 0; i < 6; ++i) { J[i] = seg[s * 6 + i]; r[i] = seg[96 + s * 6 + i]; }
    float rdM[6];
#pragma unroll
    for (int i = 0; i < 6; ++i) {
      float a = 0.f;
#pragma unroll
      for (int j = 0; j < 6; ++j) a += M[midx(i, j)] * r[j];
      rdM[i] = a;
    }
    float s1 = 0.f, s2 = 0.f;
#pragma unroll
    for (int i = 0; i < 6; ++i) { s1 += rdM[i] * r[i]; s2 += rdM[i] * rdM[i]; }
    msp[s] = (1.f - alpha) * s1 + alpha * s2;
    float dJ[6];
#pragma unroll
    for (int i = 0; i < 6; ++i) dJ[i] = decay * J[i];
#pragma unroll
    for (int i = 0; i < 6; ++i)
#pragma unroll
      for (int j = i; j < 6; ++j)
        M[midx(i, j)] = decay * M[midx(i, j)] + dJ[i] * J[j];
  }
}

// ============ combine (fused gated-mean): attnin = seq + gm*mv  (f16 out) ============
__global__ __launch_bounds__(256) void combine_kernel(const _Float16* __restrict__ seq,
    const _Float16* __restrict__ mega, const float* __restrict__ ms,
    const float* __restrict__ gate, const float* __restrict__ mem_scale,
    _Float16* __restrict__ outp) {
  const int bt = blockIdx.x;
  const int b = bt >> 10, t = bt & 1023;
  __shared__ float hterm[16];
  const int tid = threadIdx.x;
  if (tid < 16) {
    const float sc = ms[(size_t)(b * 16 + tid) * 1024 + t];
    const float gt = gate[(size_t)bt * 16 + tid];
    hterm[tid] = (1.f / (1.f + __expf(-sc * mem_scale[tid]))) * gt;
  }
  __syncthreads();
  float acc = 0.f;
#pragma unroll
  for (int h = 0; h < 16; ++h) acc += hterm[h];
  const float g = acc * (1.f / 16.f);
  const f16x4 s4 = *(const f16x4*)(seq + (size_t)bt * 1024 + tid * 4);
  const f16x4 m4 = *(const f16x4*)(mega + (size_t)bt * QS + 3072 + tid * 4);
  f16x4 o;
#pragma unroll
  for (int j = 0; j < 4; ++j) o[j] = (_Float16)((float)s4[j] + g * (float)m4[j]);
  *(f16x4*)(outp + (size_t)bt * 1024 + tid * 4) = o;
}

// ============ dst = src + bias  (pre-init for atomic split-K GEMMs) ============
__global__ void addb_init(const float* __restrict__ src, const float* __restrict__ bias,
                          float* __restrict__ dst) {
  const size_t i = (size_t)blockIdx.x * 256 + threadIdx.x;
  const int c4 = (int)(i & 255);
  const float4 s = ((const float4*)src)[i];
  const float4 b = ((const float4*)bias)[c4];
  float4 o;
  o.x = s.x + b.x; o.y = s.y + b.y; o.z = s.z + b.z; o.w = s.w + b.w;
  ((float4*)dst)[i] = o;
}

extern "C" void kernel_launch(void* const* d_in, const int* in_sizes, int n_in,
                              void* d_out, int out_size, void* d_ws, size_t ws_size,
                              hipStream_t stream) {
  (void)in_sizes; (void)n_in; (void)out_size; (void)ws_size;
  const float* x       = (const float*)d_in[0];
  const float* ln1_g   = (const float*)d_in[1];
  const float* ln1_b   = (const float*)d_in[2];
  const float* Wqkv    = (const float*)d_in[3];
  const float* bqkv    = (const float*)d_in[4];
  const float* W1w     = (const float*)d_in[5];
  const float* W2w     = (const float*)d_in[6];
  const float* W1r     = (const float*)d_in[7];
  const float* W2r     = (const float*)d_in[8];
  const float* Wmv     = (const float*)d_in[9];
  const float* bmv     = (const float*)d_in[10];
  const float* Wmg     = (const float*)d_in[11];
  const float* bmg     = (const float*)d_in[12];
  const float* mscale  = (const float*)d_in[13];
  const float* itermix = (const float*)d_in[14];
  const float* dlogits = (const float*)d_in[15];
  const float* Wout    = (const float*)d_in[16];
  const float* bout    = (const float*)d_in[17];
  const float* ln2_g   = (const float*)d_in[18];
  const float* ln2_b   = (const float*)d_in[19];
  const float* Wfc     = (const float*)d_in[20];
  const float* bfc     = (const float*)d_in[21];
  const float* Wproj   = (const float*)d_in[22];
  const float* bproj   = (const float*)d_in[23];
  float* out = (float*)d_out;
  char* wsb = (char*)d_ws;

  const size_t MB = 1u << 20;
  _Float16* h16     = (_Float16*)(wsb);              // 4MB
  _Float16* WmT     = (_Float16*)(wsb + 4 * MB);     // 9MB (4608x1024)
  float*    bm      = (float*)(wsb + 13 * MB);       // 18KB
  float*    jw      = (float*)(wsb + 13 * MB + 262144);   // 768KB
  float*    rd      = (float*)(wsb + 14 * MB);       // 768KB
  float*    gate    = (float*)(wsb + 14 * MB + 786432);   // 128KB
  float*    ms      = (float*)(wsb + 14 * MB + 917504);   // 128KB
  float*    y       = (float*)(wsb + 15 * MB);       // 8MB
  _Float16* mega1   = (_Float16*)(wsb + 23 * MB);    // 16MB (2048x4096)
  _Float16* fc16    = (_Float16*)(wsb + 23 * MB);    // reuses mega1 (dead by then)
  _Float16* lines16 = (_Float16*)(wsb + 39 * MB);    // 2MB (2048x512)
  _Float16* seq16   = (_Float16*)(wsb + 41 * MB);    // 4MB
  _Float16* WoutT   = (_Float16*)(wsb + 45 * MB);    // 2MB
  _Float16* WfcT    = (_Float16*)(wsb + 47 * MB);    // 8MB
  _Float16* WprojT  = (_Float16*)(wsb + 55 * MB);    // 8MB -> ends 63MB

  // ---- weight prep (transpose + f16) ----
  prep_megaT<<<dim3(72, 16), 256, 0, stream>>>(Wqkv, W1w, W2w, W1r, W2r, Wmg, Wmv, WmT);
  bm_init<<<18, 256, 0, stream>>>(bqkv, bmg, bmv, bm);
  transT<<<dim3(16, 16), 256, 0, stream>>>(Wout, WoutT, 1024, 1024);
  transT<<<dim3(64, 16), 256, 0, stream>>>(Wfc, WfcT, 1024, 4096);
  transT<<<dim3(16, 64), 256, 0, stream>>>(Wproj, WprojT, 4096, 1024);

  // ---- block ----
  ln16<<<2048, 256, 0, stream>>>(x, ln1_g, ln1_b, h16);
  // mega1: [qkv|mv] N=4096: 16 rows x 16 cols = 256 blocks
  gemm8<<<256, 512, 0, stream>>>(h16, WmT, bm, mega1, 4096, 1024, 0, 1, 16);
  // lines: N=512: 16 x 2 = 32 blocks (weights rows 4096.., bias 4096..)
  gemm8<<<32, 512, 0, stream>>>(h16, WmT + (size_t)4096 * 1024, bm + 4096, lines16, 512, 1024, 0, 1, 16);
  attn_mfma<<<dim3(16, 16, 2), 256, 0, stream>>>(mega1, seq16);
  lines_post<<<128, 256, 0, stream>>>(lines16, jw, rd, gate);
  gram_scan<<<32, 64, 0, stream>>>(jw, rd, dlogits, itermix, ms);
  combine_kernel<<<2048, 256, 0, stream>>>(seq16, mega1, ms, gate, mscale, h16);
  // y = x + bout + attnin @ Wout   (split-K=4: 64 blocks x 4 chunks, 4 K-tiles each)
  addb_init<<<2048, 256, 0, stream>>>(x, bout, y);
  gemm8<<<dim3(64, 4), 512, 0, stream>>>(h16, WoutT, nullptr, y, 1024, 1024, 0, 2, 4);
  ln16<<<2048, 256, 0, stream>>>(y, ln2_g, ln2_b, h16);
  // fc = gelu(h2 @ Wfc + bfc), stored f16 (overwrites mega1): 16 x 16 = 256 blocks
  gemm8<<<256, 512, 0, stream>>>(h16, WfcT, bfc, fc16, 4096, 1024, 1, 1, 16);
  // out = y + bproj + fc @ Wproj   (split-K=4: 64 x 4, K-chunk 1024 = 16 tiles)
  addb_init<<<2048, 256, 0, stream>>>(y, bproj, out);
  gemm8<<<dim3(64, 4), 512, 0, stream>>>(fc16, WprojT, nullptr, out, 1024, 4096, 0, 2, 16);
}

// Round 12
// 264.270 us; speedup vs baseline: 1.1153x; 1.1153x over previous
//
#include <hip/hip_runtime.h>
#include <hip/hip_bf16.h>
#include <math.h>

typedef float f32x4 __attribute__((ext_vector_type(4)));
typedef _Float16 f16x8 __attribute__((ext_vector_type(8)));
typedef _Float16 f16x4 __attribute__((ext_vector_type(4)));

#define TT 1024
#define DD 1024
#define QS 4608   // mega row stride (f16): [qkv 3072 | lines 512 | mv 1024]

typedef __attribute__((address_space(1))) const void gas_void;
typedef __attribute__((address_space(3))) void las_void;
static __device__ __forceinline__ void gl_lds16(const void* g, void* l) {
  __builtin_amdgcn_global_load_lds((gas_void*)g, (las_void*)l, 16, 0, 0);
}

// ============ f16 GEMM: 64x128 tile, 256 thr (4 waves of 32x64), BK=32, dbuf + counted vmcnt ============
// Many-small-blocks design: grids of 1024-1152 blocks -> 4+ blocks/CU so inter-block overlap hides
// barrier/latency stalls (m102: same structure 320 TF @256 blocks vs 912 TF @1024 blocks).
// A[2048][K] f16, Wt[N][K] f16. C = A·Wt^T (+bias)(+gelu). M fixed 2048 -> 32 row-tiles;
// wg & 31 = row-tile, wg >> 5 = col-tile (XCD-swizzled). LDS: 2 x {A 64x32 (4KB) + B 128x32 (8KB)} = 24KB.
// Per K-tile: 3 gl_lds/thread; loop = {stage(t+1) -> vmcnt(3) -> bar -> 6 ds_read + 8 MFMA -> bar}.
// Swizzle: LDS pos q of row r holds chunk q^((r>>1)&3); staged via pre-swizzled global src (rule 21).
// mode: 1 = store f16, 2 = atomicAdd f32 (pre-initialized buffer; bias ignored)
__global__ __launch_bounds__(256) void gemm_t16(
    const _Float16* __restrict__ A, const _Float16* __restrict__ Wt,
    const float* __restrict__ bias, void* __restrict__ Cv,
    int N, int K, int act, int mode, int nt) {
  __shared__ __align__(16) _Float16 As[2][2048];   // 64x32
  __shared__ __align__(16) _Float16 Bs[2][4096];   // 128x32
  const int tid = threadIdx.x;
  const int lane = tid & 63;
  const int wid = tid >> 6;                 // 0..3
  const int wr = wid >> 1, wc = wid & 1;    // 2x2 waves; wave tile 32r x 64c
  const int g = lane >> 4, l16 = lane & 15;
  const int cpx = gridDim.x >> 3;
  const int wg = (blockIdx.x & 7) * cpx + (blockIdx.x >> 3);   // XCD swizzle
  const int row0 = (wg & 31) * 64;
  const int col0 = (wg >> 5) * 128;
  const int kbeg = blockIdx.y * nt * 32;

  f32x4 acc[2][4];
#pragma unroll
  for (int m = 0; m < 2; ++m)
#pragma unroll
    for (int n = 0; n < 4; ++n) acc[m][n] = (f32x4){0.f, 0.f, 0.f, 0.f};

  // staging geometry: A = 1 load/thread (row tid>>2), B = 2 loads (rows tid>>2, 64+tid>>2)
  const int srow = tid >> 2;
  const int goff = ((tid & 3) ^ ((srow >> 1) & 3)) << 3;
  const _Float16* agp = A + (size_t)(row0 + srow) * K + kbeg + goff;
  const _Float16* bgp0 = Wt + (size_t)(col0 + srow) * K + kbeg + goff;
  const _Float16* bgp1 = Wt + (size_t)(col0 + 64 + srow) * K + kbeg + goff;
  const int ldst = tid * 16;  // bytes

  const int prm = (l16 >> 1) & 3;  // fragment-read chunk perm

#define STAGE(T, B) {                                        \
    const int kp_ = (T) * 32;                                \
    gl_lds16(agp + kp_, (char*)As[B] + ldst);                \
    gl_lds16(bgp0 + kp_, (char*)Bs[B] + ldst);               \
    gl_lds16(bgp1 + kp_, (char*)Bs[B] + 4096 + ldst); }

  STAGE(0, 0);
  for (int kt = 0; kt < nt; ++kt) {
    if (kt + 1 < nt) {
      STAGE(kt + 1, (kt + 1) & 1);
      asm volatile("s_waitcnt vmcnt(3)" ::: "memory");   // stage(kt) done; t+1's 3 in flight
    } else {
      asm volatile("s_waitcnt vmcnt(0)" ::: "memory");
    }
    __builtin_amdgcn_s_barrier();        // raw barrier (no vmcnt drain)
    __builtin_amdgcn_sched_barrier(0);   // no ds_read hoisted above
    const int cb = kt & 1;
    f16x8 af[2], bf[4];
#pragma unroll
    for (int m = 0; m < 2; ++m) {
      const int r = wr * 32 + m * 16 + l16;
      af[m] = *(const f16x8*)(As[cb] + r * 32 + ((g ^ prm) << 3));
    }
#pragma unroll
    for (int n = 0; n < 4; ++n) {
      const int c = wc * 64 + n * 16 + l16;
      bf[n] = *(const f16x8*)(Bs[cb] + c * 32 + ((g ^ prm) << 3));
    }
#pragma unroll
    for (int m = 0; m < 2; ++m)
#pragma unroll
      for (int n = 0; n < 4; ++n)
        acc[m][n] = __builtin_amdgcn_mfma_f32_16x16x32_f16(af[m], bf[n], acc[m][n], 0, 0, 0);
    __builtin_amdgcn_s_barrier();        // all reads of buf[cb] done before it is restaged
  }
#undef STAGE

#pragma unroll
  for (int m = 0; m < 2; ++m) {
#pragma unroll
    for (int n = 0; n < 4; ++n) {
      const int col = col0 + wc * 64 + n * 16 + l16;
      const float bv = (mode != 2 && bias) ? bias[col] : 0.f;
#pragma unroll
      for (int rg = 0; rg < 4; ++rg) {
        const int row = row0 + wr * 32 + m * 16 + g * 4 + rg;
        const size_t off = (size_t)row * N + col;
        float v = acc[m][n][rg] + bv;
        if (act == 1) v = 0.5f * v * (1.f + erff(v * 0.70710678118654752f));
        if (mode == 2) atomicAdd(&((float*)Cv)[off], v);
        else ((_Float16*)Cv)[off] = (_Float16)v;
      }
    }
  }
}

// ============ weight transpose+convert: W[K][N] f32 -> WT[N][K] f16 ============
__global__ __launch_bounds__(256) void transT(const float* __restrict__ W,
                                              _Float16* __restrict__ WT, int K, int N) {
  __shared__ float tile[64][65];
  const int n0 = blockIdx.x * 64, k0 = blockIdx.y * 64;
  const int tn = threadIdx.x & 63, tk4 = threadIdx.x >> 6;
#pragma unroll
  for (int it = 0; it < 16; ++it) {
    const int k = k0 + it * 4 + tk4;
    tile[tn][it * 4 + tk4] = W[(size_t)k * N + n0 + tn];
  }
  __syncthreads();
  const int on = threadIdx.x >> 2, ok = threadIdx.x & 3;
  f16x8 a, b;
#pragma unroll
  for (int j = 0; j < 8; ++j) {
    a[j] = (_Float16)tile[on][ok * 16 + j];
    b[j] = (_Float16)tile[on][ok * 16 + 8 + j];
  }
  _Float16* dst = WT + (size_t)(n0 + on) * K + k0 + ok * 16;
  *(f16x8*)dst = a;
  *(f16x8*)(dst + 8) = b;
}

// ============ build WmT [4608][1024] f16 (transposed mega weight) ============
__global__ __launch_bounds__(256) void prep_megaT(
    const float* __restrict__ Wqkv, const float* __restrict__ W1w, const float* __restrict__ W2w,
    const float* __restrict__ W1r, const float* __restrict__ W2r, const float* __restrict__ Wmg,
    const float* __restrict__ Wmv, _Float16* __restrict__ WmT) {
  __shared__ float tile[64][65];
  const int n0 = blockIdx.x * 64, k0 = blockIdx.y * 64;
  const int tn = threadIdx.x & 63, tk4 = threadIdx.x >> 6;
#pragma unroll
  for (int it = 0; it < 16; ++it) {
    const int k = k0 + it * 4 + tk4;
    const int n = n0 + tn;
    float v;
    if (n < 3072) v = Wqkv[(size_t)k * 3072 + n];
    else if (n < 3136) v = W1w[k * 64 + n - 3072];
    else if (n < 3200) v = W2w[k * 64 + n - 3136];
    else if (n < 3264) v = W1r[k * 64 + n - 3200];
    else if (n < 3328) v = W2r[k * 64 + n - 3264];
    else if (n < 3344) v = Wmg[k * 16 + n - 3328];
    else if (n < 3584) v = 0.f;
    else v = Wmv[(size_t)k * 1024 + n - 3584];
    tile[tn][it * 4 + tk4] = v;
  }
  __syncthreads();
  const int on = threadIdx.x >> 2, ok = threadIdx.x & 3;
  f16x8 a, b;
#pragma unroll
  for (int j = 0; j < 8; ++j) {
    a[j] = (_Float16)tile[on][ok * 16 + j];
    b[j] = (_Float16)tile[on][ok * 16 + 8 + j];
  }
  _Float16* dst = WmT + (size_t)(n0 + on) * 1024 + k0 + ok * 16;
  *(f16x8*)dst = a;
  *(f16x8*)(dst + 8) = b;
}

__global__ void bm_init(const float* __restrict__ bqkv, const float* __restrict__ bmg,
                        const float* __restrict__ bmv, float* __restrict__ bm) {
  const int col = blockIdx.x * 256 + threadIdx.x;
  if (col >= 4608) return;
  float b = 0.f;
  if (col < 3072) b = bqkv[col];
  else if (col >= 3328 && col < 3344) b = bmg[col - 3328];
  else if (col >= 3584) b = bmv[col - 3584];
  bm[col] = b;
}

// ============ LayerNorm -> f16 ============
__global__ __launch_bounds__(256) void ln16(const float* __restrict__ in,
    const float* __restrict__ gw, const float* __restrict__ bw, _Float16* __restrict__ out) {
  const int row = blockIdx.x, tid = threadIdx.x;
  const float* x = in + (size_t)row * DD;
  const float4 v = *(const float4*)(x + tid * 4);
  float s = v.x + v.y + v.z + v.w;
  float sq = v.x * v.x + v.y * v.y + v.z * v.z + v.w * v.w;
#pragma unroll
  for (int off = 32; off >= 1; off >>= 1) { s += __shfl_xor(s, off); sq += __shfl_xor(sq, off); }
  __shared__ float red[8];
  const int lane = tid & 63, wv = tid >> 6;
  if (lane == 0) { red[wv] = s; red[4 + wv] = sq; }
  __syncthreads();
  s = red[0] + red[1] + red[2] + red[3];
  sq = red[4] + red[5] + red[6] + red[7];
  const float mean = s * (1.f / 1024.f);
  const float var = sq * (1.f / 1024.f) - mean * mean;
  const float rstd = rsqrtf(var + 1e-5f);
  const float4 g4 = *(const float4*)(gw + tid * 4);
  const float4 b4 = *(const float4*)(bw + tid * 4);
  f16x4 o;
  o[0] = (_Float16)((v.x - mean) * rstd * g4.x + b4.x);
  o[1] = (_Float16)((v.y - mean) * rstd * g4.y + b4.y);
  o[2] = (_Float16)((v.z - mean) * rstd * g4.z + b4.z);
  o[3] = (_Float16)((v.w - mean) * rstd * g4.w + b4.w);
  *(f16x4*)(out + (size_t)row * DD + tid * 4) = o;
}

// ============ MFMA f16 causal flash attention (f16 qkv input) ============
static __device__ __forceinline__ int swzA(int row, int k) {
  return row * 64 + ((((k >> 3) ^ row) & 7) << 3) + (k & 7);
}
static __device__ __forceinline__ int swzV(int row, int k) {
  return row * 64 + ((((k >> 3) ^ row ^ (row >> 3)) & 7) << 3) + (k & 7);
}

__global__ __launch_bounds__(256) void attn_mfma(const _Float16* __restrict__ qkv,
                                                 _Float16* __restrict__ seq_out) {
  __shared__ __align__(16) _Float16 Kl[64 * 64];
  __shared__ __align__(16) _Float16 Vt[64 * 64];
  __shared__ __align__(16) _Float16 Pl[4][16 * 64];
  const int tid = threadIdx.x, lane = tid & 63, wq = tid >> 6;
  const int g = lane >> 4, l16 = lane & 15;
  const int qt = blockIdx.x, hh = blockIdx.y, bb = blockIdx.z;
  const int nt = qt + 1;

  f16x8 qf[2];
  {
    const _Float16* qp = qkv + (size_t)(bb * TT + qt * 64 + wq * 16 + l16) * QS + hh * 64;
#pragma unroll
    for (int ks = 0; ks < 2; ++ks) {
      const f16x8 a = *(const f16x8*)(qp + ks * 32 + g * 8);
#pragma unroll
      for (int j = 0; j < 8; ++j) qf[ks][j] = (_Float16)((float)a[j] * 0.125f);
    }
  }

  f32x4 oacc[4];
#pragma unroll
  for (int n = 0; n < 4; ++n) oacc[n] = (f32x4){0.f, 0.f, 0.f, 0.f};
  float m[4] = {-INFINITY, -INFINITY, -INFINITY, -INFINITY};
  float l[4] = {0.f, 0.f, 0.f, 0.f};

  const int skey = tid >> 2, sc4 = tid & 3;

  for (int tt = 0; tt < nt; ++tt) {
    if (tt) __syncthreads();
    {
      const _Float16* kp = qkv + (size_t)(bb * TT + tt * 64 + skey) * QS + hh * 64 + 1024;
      const _Float16* vp = kp + 1024;
#pragma unroll
      for (int ii = 0; ii < 4; ++ii) {
        const int d0 = sc4 * 4 + ii * 16;
        *(f16x4*)(Kl + swzA(skey, d0)) = *(const f16x4*)(kp + d0);
        const f16x4 vv = *(const f16x4*)(vp + d0);
        Vt[swzV(d0 + 0, skey)] = vv[0];
        Vt[swzV(d0 + 1, skey)] = vv[1];
        Vt[swzV(d0 + 2, skey)] = vv[2];
        Vt[swzV(d0 + 3, skey)] = vv[3];
      }
    }
    __syncthreads();
    f32x4 s[4];
#pragma unroll
    for (int n = 0; n < 4; ++n) s[n] = (f32x4){0.f, 0.f, 0.f, 0.f};
#pragma unroll
    for (int ks = 0; ks < 2; ++ks) {
      f16x8 kf[4];
#pragma unroll
      for (int n = 0; n < 4; ++n) kf[n] = *(const f16x8*)(Kl + swzA(n * 16 + l16, ks * 32 + g * 8));
#pragma unroll
      for (int n = 0; n < 4; ++n)
        s[n] = __builtin_amdgcn_mfma_f32_16x16x32_f16(qf[ks], kf[n], s[n], 0, 0, 0);
    }
    if (tt == qt) {
      const int rloc = wq * 16 + g * 4;
#pragma unroll
      for (int n = 0; n < 4; ++n) {
        const int cloc = n * 16 + l16;
#pragma unroll
        for (int reg = 0; reg < 4; ++reg)
          if (cloc > rloc + reg) s[n][reg] = -INFINITY;
      }
    }
    float f[4];
#pragma unroll
    for (int reg = 0; reg < 4; ++reg) {
      float t = fmaxf(fmaxf(s[0][reg], s[1][reg]), fmaxf(s[2][reg], s[3][reg]));
#pragma unroll
      for (int off = 1; off < 16; off <<= 1) t = fmaxf(t, __shfl_xor(t, off));
      const float nm = fmaxf(m[reg], t);
      f[reg] = __expf(m[reg] - nm);
      m[reg] = nm;
    }
    float rs[4] = {0.f, 0.f, 0.f, 0.f};
#pragma unroll
    for (int n = 0; n < 4; ++n) {
#pragma unroll
      for (int reg = 0; reg < 4; ++reg) {
        const float p = __expf(s[n][reg] - m[reg]);
        rs[reg] += p;
        Pl[wq][swzA(g * 4 + reg, n * 16 + l16)] = (_Float16)p;
      }
    }
#pragma unroll
    for (int reg = 0; reg < 4; ++reg) {
      float t = rs[reg];
#pragma unroll
      for (int off = 1; off < 16; off <<= 1) t += __shfl_xor(t, off);
      l[reg] = l[reg] * f[reg] + t;
    }
#pragma unroll
    for (int n = 0; n < 4; ++n)
#pragma unroll
      for (int reg = 0; reg < 4; ++reg) oacc[n][reg] *= f[reg];
#pragma unroll
    for (int ks = 0; ks < 2; ++ks) {
      const f16x8 pa = *(const f16x8*)(Pl[wq] + swzA(l16, ks * 32 + g * 8));
      f16x8 vb[4];
#pragma unroll
      for (int n = 0; n < 4; ++n) vb[n] = *(const f16x8*)(Vt + swzV(n * 16 + l16, ks * 32 + g * 8));
#pragma unroll
      for (int n = 0; n < 4; ++n)
        oacc[n] = __builtin_amdgcn_mfma_f32_16x16x32_f16(pa, vb[n], oacc[n], 0, 0, 0);
    }
  }
#pragma unroll
  for (int n = 0; n < 4; ++n) {
#pragma unroll
    for (int reg = 0; reg < 4; ++reg) {
      const int r = qt * 64 + wq * 16 + g * 4 + reg;
      seq_out[(size_t)(bb * TT + r) * DD + hh * 64 + n * 16 + l16] = (_Float16)(oacc[n][reg] / l[reg]);
    }
  }
}

// ============ exterior products -> Jw, rd, gate (f16 mega input) ============
static __device__ __forceinline__ void ext6(const float* a, const float* b, float* L) {
  L[0] = a[0] * b[1] - a[1] * b[0];
  L[1] = a[0] * b[2] - a[2] * b[0];
  L[2] = a[0] * b[3] - a[3] * b[0];
  L[3] = a[1] * b[2] - a[2] * b[1];
  L[4] = a[1] * b[3] - a[3] * b[1];
  L[5] = a[2] * b[3] - a[3] * b[2];
  const float n = sqrtf(L[0]*L[0] + L[1]*L[1] + L[2]*L[2] + L[3]*L[3] + L[4]*L[4] + L[5]*L[5]);
  const float s = 1.f / fmaxf(n, 1e-12f);
#pragma unroll
  for (int i = 0; i < 6; ++i) L[i] *= s;
}

__global__ void lines_post(const _Float16* __restrict__ mega, float* __restrict__ jw,
                           float* __restrict__ rdv, float* __restrict__ gate) {
  const int idx = blockIdx.x * 256 + threadIdx.x;
  const int h = idx & 15;
  const int bt = idx >> 4;
  const int t = bt & 1023;
  const int b = bt >> 10;
  const _Float16* row = mega + (size_t)bt * QS + 3072;
  float w1[4] = {0.f, 0.f, 0.f, 0.f}, w2[4], r1[4], r2[4];
  if (t > 0) {
#pragma unroll
    for (int i = 0; i < 4; ++i) w1[i] = (float)row[-QS + h * 4 + i];
  }
#pragma unroll
  for (int i = 0; i < 4; ++i) {
    w2[i] = (float)row[64 + h * 4 + i];
    r1[i] = (float)row[128 + h * 4 + i];
    r2[i] = (float)row[192 + h * 4 + i];
  }
  const float gp = (float)row[256 + h];
  float wl[6], rl[6];
  ext6(w1, w2, wl);
  ext6(r1, r2, rl);
  const size_t o = ((size_t)(b * 16 + h) * 1024 + t) * 6;
  jw[o + 0] =  wl[5]; jw[o + 1] = -wl[4]; jw[o + 2] =  wl[3];
  jw[o + 3] =  wl[2]; jw[o + 4] = -wl[1]; jw[o + 5] =  wl[0];
#pragma unroll
  for (int i = 0; i < 6; ++i) rdv[o + i] = rl[i];
  gate[idx] = 1.f / (1.f + __expf(-gp));
}

// ============ chunk-parallel Gram scan ============
static __device__ __forceinline__ int midx(int i, int j) {
  return (i <= j) ? (i * (13 - i)) / 2 + (j - i) : (j * (13 - j)) / 2 + (i - j);
}

__global__ __launch_bounds__(64) void gram_scan(const float* __restrict__ jwv,
    const float* __restrict__ rdv, const float* __restrict__ decay_logits,
    const float* __restrict__ iter_mix, float* __restrict__ mem_score) {
  const int h = blockIdx.x & 15, b = blockIdx.x >> 4;
  const int lane = threadIdx.x;
  const float decay = 1.f / (1.f + __expf(-decay_logits[h]));
  const float alpha = 1.f / (1.f + __expf(-iter_mix[0]));
  __shared__ float sd[64 * 193];
  const size_t base = (size_t)(b * 16 + h) * 1024 * 6;
  for (int it = 0; it < 96; ++it) {
    const int idx = it * 64 + lane;
    const int t = idx / 6, i = idx - 6 * t;
    const int ld = t >> 4, s = t & 15;
    sd[ld * 193 + s * 6 + i] = jwv[base + idx];
    sd[ld * 193 + 96 + s * 6 + i] = rdv[base + idx];
  }
  __syncthreads();
  const float* seg = sd + lane * 193;

  float C[21];
#pragma unroll
  for (int e = 0; e < 21; ++e) C[e] = 0.f;
  for (int s = 0; s < 16; ++s) {
    float J[6], dJ[6];
#pragma unroll
    for (int i = 0; i < 6; ++i) { J[i] = seg[s * 6 + i]; dJ[i] = decay * J[i]; }
#pragma unroll
    for (int i = 0; i < 6; ++i)
#pragma unroll
      for (int j = i; j < 6; ++j)
        C[midx(i, j)] = decay * C[midx(i, j)] + dJ[i] * J[j];
  }
  const float d2 = decay * decay, d4 = d2 * d2, d8 = d4 * d4;
  float fk = d8 * d8;  // d^16
#pragma unroll
  for (int k = 0; k < 6; ++k) {
    const int off = 1 << k;
#pragma unroll
    for (int e = 0; e < 21; ++e) {
      const float u = __shfl(C[e], lane - off);
      if (lane >= off) C[e] += fk * u;
    }
    fk = fk * fk;
  }
  float M[21];
#pragma unroll
  for (int e = 0; e < 21; ++e) {
    const float u = __shfl(C[e], lane - 1);
    M[e] = (lane >= 1) ? u : 0.f;
  }
  float* msp = mem_score + (size_t)(b * 16 + h) * 1024 + lane * 16;
  for (int s = 0; s < 16; ++s) {
    float J[6], r[6];
#pragma unroll
    for (int i = 0; i < 6; ++i) { J[i] = seg[s * 6 + i]; r[i] = seg[96 + s * 6 + i]; }
    float rdM[6];
#pragma unroll
    for (int i = 0; i < 6; ++i) {
      float a = 0.f;
#pragma unroll
      for (int j = 0; j < 6; ++j) a += M[midx(i, j)] * r[j];
      rdM[i] = a;
    }
    float s1 = 0.f, s2 = 0.f;
#pragma unroll
    for (int i = 0; i < 6; ++i) { s1 += rdM[i] * r[i]; s2 += rdM[i] * rdM[i]; }
    msp[s] = (1.f - alpha) * s1 + alpha * s2;
    float dJ[6];
#pragma unroll
    for (int i = 0; i < 6; ++i) dJ[i] = decay * J[i];
#pragma unroll
    for (int i = 0; i < 6; ++i)
#pragma unroll
      for (int j = i; j < 6; ++j)
        M[midx(i, j)] = decay * M[midx(i, j)] + dJ[i] * J[j];
  }
}

// ============ combine (fused gated-mean): attnin = seq + gm*mv  (f16 out) ============
__global__ __launch_bounds__(256) void combine_kernel(const _Float16* __restrict__ seq,
    const _Float16* __restrict__ mega, const float* __restrict__ ms,
    const float* __restrict__ gate, const float* __restrict__ mem_scale,
    _Float16* __restrict__ outp) {
  const int bt = blockIdx.x;
  const int b = bt >> 10, t = bt & 1023;
  __shared__ float hterm[16];
  const int tid = threadIdx.x;
  if (tid < 16) {
    const float sc = ms[(size_t)(b * 16 + tid) * 1024 + t];
    const float gt = gate[(size_t)bt * 16 + tid];
    hterm[tid] = (1.f / (1.f + __expf(-sc * mem_scale[tid]))) * gt;
  }
  __syncthreads();
  float acc = 0.f;
#pragma unroll
  for (int h = 0; h < 16; ++h) acc += hterm[h];
  const float g = acc * (1.f / 16.f);
  const f16x4 s4 = *(const f16x4*)(seq + (size_t)bt * 1024 + tid * 4);
  const f16x4 m4 = *(const f16x4*)(mega + (size_t)bt * QS + 3584 + tid * 4);
  f16x4 o;
#pragma unroll
  for (int j = 0; j < 4; ++j) o[j] = (_Float16)((float)s4[j] + g * (float)m4[j]);
  *(f16x4*)(outp + (size_t)bt * 1024 + tid * 4) = o;
}

// ============ dst = src + bias  (pre-init for atomic split-K GEMMs) ============
__global__ void addb_init(const float* __restrict__ src, const float* __restrict__ bias,
                          float* __restrict__ dst) {
  const size_t i = (size_t)blockIdx.x * 256 + threadIdx.x;
  const int c4 = (int)(i & 255);
  const float4 s = ((const float4*)src)[i];
  const float4 b = ((const float4*)bias)[c4];
  float4 o;
  o.x = s.x + b.x; o.y = s.y + b.y; o.z = s.z + b.z; o.w = s.w + b.w;
  ((float4*)dst)[i] = o;
}

extern "C" void kernel_launch(void* const* d_in, const int* in_sizes, int n_in,
                              void* d_out, int out_size, void* d_ws, size_t ws_size,
                              hipStream_t stream) {
  (void)in_sizes; (void)n_in; (void)out_size; (void)ws_size;
  const float* x       = (const float*)d_in[0];
  const float* ln1_g   = (const float*)d_in[1];
  const float* ln1_b   = (const float*)d_in[2];
  const float* Wqkv    = (const float*)d_in[3];
  const float* bqkv    = (const float*)d_in[4];
  const float* W1w     = (const float*)d_in[5];
  const float* W2w     = (const float*)d_in[6];
  const float* W1r     = (const float*)d_in[7];
  const float* W2r     = (const float*)d_in[8];
  const float* Wmv     = (const float*)d_in[9];
  const float* bmv     = (const float*)d_in[10];
  const float* Wmg     = (const float*)d_in[11];
  const float* bmg     = (const float*)d_in[12];
  const float* mscale  = (const float*)d_in[13];
  const float* itermix = (const float*)d_in[14];
  const float* dlogits = (const float*)d_in[15];
  const float* Wout    = (const float*)d_in[16];
  const float* bout    = (const float*)d_in[17];
  const float* ln2_g   = (const float*)d_in[18];
  const float* ln2_b   = (const float*)d_in[19];
  const float* Wfc     = (const float*)d_in[20];
  const float* bfc     = (const float*)d_in[21];
  const float* Wproj   = (const float*)d_in[22];
  const float* bproj   = (const float*)d_in[23];
  float* out = (float*)d_out;
  float* ws = (float*)d_ws;

  const size_t M1 = 1u << 20;
  _Float16* h16    = (_Float16*)ws;                         // 0 .. 1M1 (2M f16)
  _Float16* WmT    = (_Float16*)(ws + 1 * M1);              // 1M1 .. 3.25M1
  float*    bm     = ws + 3407872;                          // 3.25M1, 4608
  float*    jw     = ws + 3538944;                          // 3.375M1, 196608
  float*    rd     = ws + 3538944 + 196608;
  float*    gate   = ws + 3538944 + 393216;                 // 32768
  float*    ms     = ws + 3538944 + 425984;                 // 32768
  float*    y      = ws + 4 * M1;                           // 4M1 .. 6M1
  _Float16* mega   = (_Float16*)(ws + 6 * M1);              // 6M1 .. 10.5M1 (2048x4608 f16)
  _Float16* fc16   = (_Float16*)(ws + 6 * M1);              // reuses mega (dead by then)
  _Float16* seq16  = (_Float16*)(ws + 11010048);            // 10.5M1 .. 11.5M1
  _Float16* WoutT  = (_Float16*)(ws + 12058624);            // 11.5M1 .. 12M1
  _Float16* WfcT   = (_Float16*)(ws + 12 * M1);             // 12M1 .. 14M1 (4096x1024 f16)
  _Float16* WprojT = (_Float16*)(ws + 14 * M1);             // 14M1 .. 16M1 (1024x4096 f16)

  // ---- weight prep (transpose + f16) ----
  prep_megaT<<<dim3(72, 16), 256, 0, stream>>>(Wqkv, W1w, W2w, W1r, W2r, Wmg, Wmv, WmT);
  bm_init<<<18, 256, 0, stream>>>(bqkv, bmg, bmv, bm);
  transT<<<dim3(16, 16), 256, 0, stream>>>(Wout, WoutT, 1024, 1024);
  transT<<<dim3(64, 16), 256, 0, stream>>>(Wfc, WfcT, 1024, 4096);
  transT<<<dim3(16, 64), 256, 0, stream>>>(Wproj, WprojT, 4096, 1024);

  // ---- block ----
  ln16<<<2048, 256, 0, stream>>>(x, ln1_g, ln1_b, h16);
  // mega: 32 row-tiles x 36 col-tiles = 1152 blocks (~4.5/CU)
  gemm_t16<<<1152, 256, 0, stream>>>(h16, WmT, bm, mega, 4608, 1024, 0, 1, 32);
  attn_mfma<<<dim3(16, 16, 2), 256, 0, stream>>>(mega, seq16);
  lines_post<<<128, 256, 0, stream>>>(mega, jw, rd, gate);
  gram_scan<<<32, 64, 0, stream>>>(jw, rd, dlogits, itermix, ms);
  combine_kernel<<<2048, 256, 0, stream>>>(seq16, mega, ms, gate, mscale, h16);
  // y = x + bout + attnin @ Wout   (split-K=4: 32x8=256 blocks x 4 chunks = 1024)
  addb_init<<<2048, 256, 0, stream>>>(x, bout, y);
  gemm_t16<<<dim3(256, 4), 256, 0, stream>>>(h16, WoutT, nullptr, y, 1024, 1024, 0, 2, 8);
  ln16<<<2048, 256, 0, stream>>>(y, ln2_g, ln2_b, h16);
  // fc = gelu(h2 @ Wfc + bfc), stored f16 (overwrites mega): 32x32 = 1024 blocks
  gemm_t16<<<1024, 256, 0, stream>>>(h16, WfcT, bfc, fc16, 4096, 1024, 1, 1, 32);
  // out = y + bproj + fc @ Wproj   (split-K=4: 256 x 4 = 1024 blocks, K-chunk 1024)
  addb_init<<<2048, 256, 0, stream>>>(y, bproj, out);
  gemm_t16<<<dim3(256, 4), 256, 0, stream>>>(fc16, WprojT, nullptr, out, 1024, 4096, 0, 2, 32);
}

// Round 13
// 235.853 us; speedup vs baseline: 1.2497x; 1.1205x over previous
//
#include <hip/hip_runtime.h>
#include <hip/hip_bf16.h>
#include <math.h>

typedef float f32x4 __attribute__((ext_vector_type(4)));
typedef _Float16 f16x8 __attribute__((ext_vector_type(8)));
typedef _Float16 f16x4 __attribute__((ext_vector_type(4)));

#define TT 1024
#define DD 1024
#define QS 4608   // mega row stride (f16): [qkv 3072 | lines 512 | mv 1024]

typedef __attribute__((address_space(1))) const void gas_void;
typedef __attribute__((address_space(3))) void las_void;
static __device__ __forceinline__ void gl_lds16(const void* g, void* l) {
  __builtin_amdgcn_global_load_lds((gas_void*)g, (las_void*)l, 16, 0, 0);
}

// ============ f16 GEMM (R9 structure): 128x128 tile, 512 thr (8 waves 4x2), BK=32, 3-slot vmcnt ring ============
// A[M][K] f16, Wt[N][K] f16 (pre-transposed). C = A·Wt^T (+bias)(+gelu).
// LDS linear [row][4 chunks of 8 f16]; content pre-swizzled: pos(row,q) holds chunk q^((row>>1)&3).
// Ring: stage(t+1) in flight across barrier (counted vmcnt(2)); stage(t+2) issued after barrier.
// mode: 1 = store f16 | 2 = atomicAdd f32 (pre-initialized buffer; bias ignored) | 3 = store f32 + bias + residual
__global__ __launch_bounds__(512) void gemm_t16(
    const _Float16* __restrict__ A, const _Float16* __restrict__ Wt,
    const float* __restrict__ bias, const float* __restrict__ residual,
    void* __restrict__ Cv, int N, int K, int act, int gx, int mode, int ktiles) {
  __shared__ __align__(16) _Float16 As[3][4096];   // 128x32 each
  __shared__ __align__(16) _Float16 Bs[3][4096];
  const int tid = threadIdx.x;
  const int lane = tid & 63;
  const int wid = tid >> 6;                 // 0..7
  const int wr = wid >> 1, wc = wid & 1;    // 4x2 wave grid; wave tile 32r x 64c
  const int g = lane >> 4, l16 = lane & 15;
  const int cpx = gridDim.x >> 3;
  const int wg = (blockIdx.x & 7) * cpx + (blockIdx.x >> 3);   // XCD swizzle
  const int row0 = (wg / gx) * 128, col0 = (wg % gx) * 128;
  const int kbeg = blockIdx.y * ktiles * 32;

  f32x4 acc[2][4];
#pragma unroll
  for (int m = 0; m < 2; ++m)
#pragma unroll
    for (int n = 0; n < 4; ++n) acc[m][n] = (f32x4){0.f, 0.f, 0.f, 0.f};

  const int srow = tid >> 2;
  const int goff = ((tid & 3) ^ ((srow >> 1) & 3)) << 3;
  const _Float16* agp = A + (size_t)(row0 + srow) * K + kbeg + goff;
  const _Float16* bgp = Wt + (size_t)(col0 + srow) * K + kbeg + goff;
  const int ldst = tid * 16;   // byte offset in tile

  const int prm = (l16 >> 1) & 3;  // fragment-read chunk perm

  // prologue: stage tiles 0 and 1 into slots 0 and 1
  gl_lds16(agp, (char*)As[0] + ldst);
  gl_lds16(bgp, (char*)Bs[0] + ldst);
  if (1 < ktiles) {
    gl_lds16(agp + 32, (char*)As[1] + ldst);
    gl_lds16(bgp + 32, (char*)Bs[1] + ldst);
  }

  int cs = 0, ss = 2;
  for (int kt = 0; kt < ktiles; ++kt) {
    if (kt < ktiles - 1) asm volatile("s_waitcnt vmcnt(2)" ::: "memory");
    else                 asm volatile("s_waitcnt vmcnt(0)" ::: "memory");
    __builtin_amdgcn_s_barrier();        // raw barrier: does NOT drain vmcnt
    __builtin_amdgcn_sched_barrier(0);   // no ds_read hoisted above the barrier
    if (kt + 2 < ktiles) {
      const int kp = (kt + 2) * 32;
      gl_lds16(agp + kp, (char*)As[ss] + ldst);
      gl_lds16(bgp + kp, (char*)Bs[ss] + ldst);
    }
    f16x8 af[2], bf[4];
#pragma unroll
    for (int m = 0; m < 2; ++m) {
      const int r = wr * 32 + m * 16 + l16;
      af[m] = *(const f16x8*)(As[cs] + r * 32 + ((g ^ prm) << 3));
    }
#pragma unroll
    for (int n = 0; n < 4; ++n) {
      const int c = wc * 64 + n * 16 + l16;
      bf[n] = *(const f16x8*)(Bs[cs] + c * 32 + ((g ^ prm) << 3));
    }
#pragma unroll
    for (int m = 0; m < 2; ++m)
#pragma unroll
      for (int n = 0; n < 4; ++n)
        acc[m][n] = __builtin_amdgcn_mfma_f32_16x16x32_f16(af[m], bf[n], acc[m][n], 0, 0, 0);
    cs = (cs == 2) ? 0 : cs + 1;
    ss = (ss == 2) ? 0 : ss + 1;
  }
#pragma unroll
  for (int m = 0; m < 2; ++m) {
#pragma unroll
    for (int n = 0; n < 4; ++n) {
      const int col = col0 + wc * 64 + n * 16 + l16;
      const float bv = (mode != 2 && bias) ? bias[col] : 0.f;
#pragma unroll
      for (int rg = 0; rg < 4; ++rg) {
        const int row = row0 + wr * 32 + m * 16 + g * 4 + rg;
        const size_t off = (size_t)row * N + col;
        float v = acc[m][n][rg] + bv;
        if (act == 1) v = 0.5f * v * (1.f + erff(v * 0.70710678118654752f));
        if (mode == 2) atomicAdd(&((float*)Cv)[off], v);
        else if (mode == 3) ((float*)Cv)[off] = v + residual[off];
        else ((_Float16*)Cv)[off] = (_Float16)v;
      }
    }
  }
}

// ============ fused weight prep: megaT + 3 transposes + biases in ONE dispatch ============
static __device__ __forceinline__ void trans_tile(const float* __restrict__ W,
    _Float16* __restrict__ WT, int K, int N, int n0, int k0, int tid) {
  __shared__ float tile[64][65];
  const int tn = tid & 63, tk4 = tid >> 6;
#pragma unroll
  for (int it = 0; it < 16; ++it) {
    const int k = k0 + it * 4 + tk4;
    tile[tn][it * 4 + tk4] = W[(size_t)k * N + n0 + tn];
  }
  __syncthreads();
  const int on = tid >> 2, ok = tid & 3;
  f16x8 a, b;
#pragma unroll
  for (int j = 0; j < 8; ++j) {
    a[j] = (_Float16)tile[on][ok * 16 + j];
    b[j] = (_Float16)tile[on][ok * 16 + 8 + j];
  }
  _Float16* dst = WT + (size_t)(n0 + on) * K + k0 + ok * 16;
  *(f16x8*)dst = a;
  *(f16x8*)(dst + 8) = b;
}

__global__ __launch_bounds__(256) void prep_all(
    const float* __restrict__ Wqkv, const float* __restrict__ W1w, const float* __restrict__ W2w,
    const float* __restrict__ W1r, const float* __restrict__ W2r, const float* __restrict__ Wmg,
    const float* __restrict__ Wmv, const float* __restrict__ Wout, const float* __restrict__ Wfc,
    const float* __restrict__ Wproj, const float* __restrict__ bqkv, const float* __restrict__ bmg,
    const float* __restrict__ bmv, _Float16* __restrict__ WmT, _Float16* __restrict__ WoutT,
    _Float16* __restrict__ WfcT, _Float16* __restrict__ WprojT, float* __restrict__ bm) {
  const int id = blockIdx.x;
  const int tid = threadIdx.x;
  if (id < 1152) {                      // megaT gather-transpose: 72 n-tiles x 16 k-tiles
    __shared__ float tile[64][65];
    const int n0 = (id % 72) * 64, k0 = (id / 72) * 64;
    const int tn = tid & 63, tk4 = tid >> 6;
#pragma unroll
    for (int it = 0; it < 16; ++it) {
      const int k = k0 + it * 4 + tk4;
      const int n = n0 + tn;
      float v;
      if (n < 3072) v = Wqkv[(size_t)k * 3072 + n];
      else if (n < 3136) v = W1w[k * 64 + n - 3072];
      else if (n < 3200) v = W2w[k * 64 + n - 3136];
      else if (n < 3264) v = W1r[k * 64 + n - 3200];
      else if (n < 3328) v = W2r[k * 64 + n - 3264];
      else if (n < 3344) v = Wmg[k * 16 + n - 3328];
      else if (n < 3584) v = 0.f;
      else v = Wmv[(size_t)k * 1024 + n - 3584];
      tile[tn][it * 4 + tk4] = v;
    }
    __syncthreads();
    const int on = tid >> 2, ok = tid & 3;
    f16x8 a, b;
#pragma unroll
    for (int j = 0; j < 8; ++j) {
      a[j] = (_Float16)tile[on][ok * 16 + j];
      b[j] = (_Float16)tile[on][ok * 16 + 8 + j];
    }
    _Float16* dst = WmT + (size_t)(n0 + on) * 1024 + k0 + ok * 16;
    *(f16x8*)dst = a;
    *(f16x8*)(dst + 8) = b;
  } else if (id < 1408) {               // WoutT: 16 x 16
    const int i2 = id - 1152;
    trans_tile(Wout, WoutT, 1024, 1024, (i2 % 16) * 64, (i2 / 16) * 64, tid);
  } else if (id < 2432) {               // WfcT: 64 x 16
    const int i2 = id - 1408;
    trans_tile(Wfc, WfcT, 1024, 4096, (i2 % 64) * 64, (i2 / 64) * 64, tid);
  } else if (id < 3456) {               // WprojT: 16 x 64
    const int i2 = id - 2432;
    trans_tile(Wproj, WprojT, 4096, 1024, (i2 % 16) * 64, (i2 / 16) * 64, tid);
  } else {                              // bm: 18 blocks x 256
    const int col = (id - 3456) * 256 + tid;
    if (col < 4608) {
      float b = 0.f;
      if (col < 3072) b = bqkv[col];
      else if (col >= 3328 && col < 3344) b = bmg[col - 3328];
      else if (col >= 3584) b = bmv[col - 3584];
      bm[col] = b;
    }
  }
}

// ============ LayerNorm -> f16 ============
__global__ __launch_bounds__(256) void ln16(const float* __restrict__ in,
    const float* __restrict__ gw, const float* __restrict__ bw, _Float16* __restrict__ out) {
  const int row = blockIdx.x, tid = threadIdx.x;
  const float* x = in + (size_t)row * DD;
  const float4 v = *(const float4*)(x + tid * 4);
  float s = v.x + v.y + v.z + v.w;
  float sq = v.x * v.x + v.y * v.y + v.z * v.z + v.w * v.w;
#pragma unroll
  for (int off = 32; off >= 1; off >>= 1) { s += __shfl_xor(s, off); sq += __shfl_xor(sq, off); }
  __shared__ float red[8];
  const int lane = tid & 63, wv = tid >> 6;
  if (lane == 0) { red[wv] = s; red[4 + wv] = sq; }
  __syncthreads();
  s = red[0] + red[1] + red[2] + red[3];
  sq = red[4] + red[5] + red[6] + red[7];
  const float mean = s * (1.f / 1024.f);
  const float var = sq * (1.f / 1024.f) - mean * mean;
  const float rstd = rsqrtf(var + 1e-5f);
  const float4 g4 = *(const float4*)(gw + tid * 4);
  const float4 b4 = *(const float4*)(bw + tid * 4);
  f16x4 o;
  o[0] = (_Float16)((v.x - mean) * rstd * g4.x + b4.x);
  o[1] = (_Float16)((v.y - mean) * rstd * g4.y + b4.y);
  o[2] = (_Float16)((v.z - mean) * rstd * g4.z + b4.z);
  o[3] = (_Float16)((v.w - mean) * rstd * g4.w + b4.w);
  *(f16x4*)(out + (size_t)row * DD + tid * 4) = o;
}

// ============ MFMA f16 causal flash attention, PAIRED q-tiles (qt=p and qt=15-p) ============
// Balanced: every block does exactly 17 MFMA tile-steps; K/V staged once, shared by both q-tiles.
static __device__ __forceinline__ int swzA(int row, int k) {
  return row * 64 + ((((k >> 3) ^ row) & 7) << 3) + (k & 7);
}
static __device__ __forceinline__ int swzV(int row, int k) {
  return row * 64 + ((((k >> 3) ^ row ^ (row >> 3)) & 7) << 3) + (k & 7);
}

static __device__ __forceinline__ void attn_step(
    const f16x8* qf, f32x4* oacc, float* m, float* l,
    const _Float16* Kl, const _Float16* Vt, _Float16* Plw,
    bool diag, int wq, int g, int l16) {
  f32x4 s[4];
#pragma unroll
  for (int n = 0; n < 4; ++n) s[n] = (f32x4){0.f, 0.f, 0.f, 0.f};
#pragma unroll
  for (int ks = 0; ks < 2; ++ks) {
    f16x8 kf[4];
#pragma unroll
    for (int n = 0; n < 4; ++n) kf[n] = *(const f16x8*)(Kl + swzA(n * 16 + l16, ks * 32 + g * 8));
#pragma unroll
    for (int n = 0; n < 4; ++n)
      s[n] = __builtin_amdgcn_mfma_f32_16x16x32_f16(qf[ks], kf[n], s[n], 0, 0, 0);
  }
  if (diag) {
    const int rloc = wq * 16 + g * 4;
#pragma unroll
    for (int n = 0; n < 4; ++n) {
      const int cloc = n * 16 + l16;
#pragma unroll
      for (int reg = 0; reg < 4; ++reg)
        if (cloc > rloc + reg) s[n][reg] = -INFINITY;
    }
  }
  float f[4];
#pragma unroll
  for (int reg = 0; reg < 4; ++reg) {
    float t = fmaxf(fmaxf(s[0][reg], s[1][reg]), fmaxf(s[2][reg], s[3][reg]));
#pragma unroll
    for (int off = 1; off < 16; off <<= 1) t = fmaxf(t, __shfl_xor(t, off));
    const float nm = fmaxf(m[reg], t);
    f[reg] = __expf(m[reg] - nm);
    m[reg] = nm;
  }
  float rs[4] = {0.f, 0.f, 0.f, 0.f};
#pragma unroll
  for (int n = 0; n < 4; ++n) {
#pragma unroll
    for (int reg = 0; reg < 4; ++reg) {
      const float p = __expf(s[n][reg] - m[reg]);
      rs[reg] += p;
      Plw[swzA(g * 4 + reg, n * 16 + l16)] = (_Float16)p;
    }
  }
#pragma unroll
  for (int reg = 0; reg < 4; ++reg) {
    float t = rs[reg];
#pragma unroll
    for (int off = 1; off < 16; off <<= 1) t += __shfl_xor(t, off);
    l[reg] = l[reg] * f[reg] + t;
  }
#pragma unroll
  for (int n = 0; n < 4; ++n)
#pragma unroll
    for (int reg = 0; reg < 4; ++reg) oacc[n][reg] *= f[reg];
#pragma unroll
  for (int ks = 0; ks < 2; ++ks) {
    const f16x8 pa = *(const f16x8*)(Plw + swzA(l16, ks * 32 + g * 8));
    f16x8 vb[4];
#pragma unroll
    for (int n = 0; n < 4; ++n) vb[n] = *(const f16x8*)(Vt + swzV(n * 16 + l16, ks * 32 + g * 8));
#pragma unroll
    for (int n = 0; n < 4; ++n)
      oacc[n] = __builtin_amdgcn_mfma_f32_16x16x32_f16(pa, vb[n], oacc[n], 0, 0, 0);
  }
}

__global__ __launch_bounds__(256) void attn_mfma(const _Float16* __restrict__ qkv,
                                                 _Float16* __restrict__ seq_out) {
  __shared__ __align__(16) _Float16 Kl[64 * 64];
  __shared__ __align__(16) _Float16 Vt[64 * 64];
  __shared__ __align__(16) _Float16 Pl[4][16 * 64];
  const int tid = threadIdx.x, lane = tid & 63, wq = tid >> 6;
  const int g = lane >> 4, l16 = lane & 15;
  const int p = blockIdx.x, hh = blockIdx.y, bb = blockIdx.z;
  const int qt0 = p, qt1 = 15 - p;
  const int ntt = qt1 + 1;

  f16x8 qf0[2], qf1[2];
  {
    const _Float16* q0 = qkv + (size_t)(bb * TT + qt0 * 64 + wq * 16 + l16) * QS + hh * 64;
    const _Float16* q1 = qkv + (size_t)(bb * TT + qt1 * 64 + wq * 16 + l16) * QS + hh * 64;
#pragma unroll
    for (int ks = 0; ks < 2; ++ks) {
      const f16x8 a0 = *(const f16x8*)(q0 + ks * 32 + g * 8);
      const f16x8 a1 = *(const f16x8*)(q1 + ks * 32 + g * 8);
#pragma unroll
      for (int j = 0; j < 8; ++j) {
        qf0[ks][j] = (_Float16)((float)a0[j] * 0.125f);
        qf1[ks][j] = (_Float16)((float)a1[j] * 0.125f);
      }
    }
  }

  f32x4 oacc0[4], oacc1[4];
#pragma unroll
  for (int n = 0; n < 4; ++n) {
    oacc0[n] = (f32x4){0.f, 0.f, 0.f, 0.f};
    oacc1[n] = (f32x4){0.f, 0.f, 0.f, 0.f};
  }
  float m0[4] = {-INFINITY, -INFINITY, -INFINITY, -INFINITY};
  float l0[4] = {0.f, 0.f, 0.f, 0.f};
  float m1[4] = {-INFINITY, -INFINITY, -INFINITY, -INFINITY};
  float l1[4] = {0.f, 0.f, 0.f, 0.f};

  const int skey = tid >> 2, sc4 = tid & 3;

  for (int tt = 0; tt < ntt; ++tt) {
    if (tt) __syncthreads();
    {
      const _Float16* kp = qkv + (size_t)(bb * TT + tt * 64 + skey) * QS + hh * 64 + 1024;
      const _Float16* vp = kp + 1024;
#pragma unroll
      for (int ii = 0; ii < 4; ++ii) {
        const int d0 = sc4 * 4 + ii * 16;
        *(f16x4*)(Kl + swzA(skey, d0)) = *(const f16x4*)(kp + d0);
        const f16x4 vv = *(const f16x4*)(vp + d0);
        Vt[swzV(d0 + 0, skey)] = vv[0];
        Vt[swzV(d0 + 1, skey)] = vv[1];
        Vt[swzV(d0 + 2, skey)] = vv[2];
        Vt[swzV(d0 + 3, skey)] = vv[3];
      }
    }
    __syncthreads();
    attn_step(qf1, oacc1, m1, l1, Kl, Vt, Pl[wq], tt == qt1, wq, g, l16);
    if (tt <= qt0)
      attn_step(qf0, oacc0, m0, l0, Kl, Vt, Pl[wq], tt == qt0, wq, g, l16);
  }
#pragma unroll
  for (int n = 0; n < 4; ++n) {
#pragma unroll
    for (int reg = 0; reg < 4; ++reg) {
      const int r0 = qt0 * 64 + wq * 16 + g * 4 + reg;
      const int r1 = qt1 * 64 + wq * 16 + g * 4 + reg;
      seq_out[(size_t)(bb * TT + r0) * DD + hh * 64 + n * 16 + l16] = (_Float16)(oacc0[n][reg] / l0[reg]);
      seq_out[(size_t)(bb * TT + r1) * DD + hh * 64 + n * 16 + l16] = (_Float16)(oacc1[n][reg] / l1[reg]);
    }
  }
}

// ============ exterior products -> Jw, rd, gate (f16 mega input) ============
static __device__ __forceinline__ void ext6(const float* a, const float* b, float* L) {
  L[0] = a[0] * b[1] - a[1] * b[0];
  L[1] = a[0] * b[2] - a[2] * b[0];
  L[2] = a[0] * b[3] - a[3] * b[0];
  L[3] = a[1] * b[2] - a[2] * b[1];
  L[4] = a[1] * b[3] - a[3] * b[1];
  L[5] = a[2] * b[3] - a[3] * b[2];
  const float n = sqrtf(L[0]*L[0] + L[1]*L[1] + L[2]*L[2] + L[3]*L[3] + L[4]*L[4] + L[5]*L[5]);
  const float s = 1.f / fmaxf(n, 1e-12f);
#pragma unroll
  for (int i = 0; i < 6; ++i) L[i] *= s;
}

__global__ void lines_post(const _Float16* __restrict__ mega, float* __restrict__ jw,
                           float* __restrict__ rdv, float* __restrict__ gate) {
  const int idx = blockIdx.x * 256 + threadIdx.x;
  const int h = idx & 15;
  const int bt = idx >> 4;
  const int t = bt & 1023;
  const int b = bt >> 10;
  const _Float16* row = mega + (size_t)bt * QS + 3072;
  float w1[4] = {0.f, 0.f, 0.f, 0.f}, w2[4], r1[4], r2[4];
  if (t > 0) {
#pragma unroll
    for (int i = 0; i < 4; ++i) w1[i] = (float)row[-QS + h * 4 + i];
  }
#pragma unroll
  for (int i = 0; i < 4; ++i) {
    w2[i] = (float)row[64 + h * 4 + i];
    r1[i] = (float)row[128 + h * 4 + i];
    r2[i] = (float)row[192 + h * 4 + i];
  }
  const float gp = (float)row[256 + h];
  float wl[6], rl[6];
  ext6(w1, w2, wl);
  ext6(r1, r2, rl);
  const size_t o = ((size_t)(b * 16 + h) * 1024 + t) * 6;
  jw[o + 0] =  wl[5]; jw[o + 1] = -wl[4]; jw[o + 2] =  wl[3];
  jw[o + 3] =  wl[2]; jw[o + 4] = -wl[1]; jw[o + 5] =  wl[0];
#pragma unroll
  for (int i = 0; i < 6; ++i) rdv[o + i] = rl[i];
  gate[idx] = 1.f / (1.f + __expf(-gp));
}

// ============ chunk-parallel Gram scan ============
static __device__ __forceinline__ int midx(int i, int j) {
  return (i <= j) ? (i * (13 - i)) / 2 + (j - i) : (j * (13 - j)) / 2 + (i - j);
}

__global__ __launch_bounds__(64) void gram_scan(const float* __restrict__ jwv,
    const float* __restrict__ rdv, const float* __restrict__ decay_logits,
    const float* __restrict__ iter_mix, float* __restrict__ mem_score) {
  const int h = blockIdx.x & 15, b = blockIdx.x >> 4;
  const int lane = threadIdx.x;
  const float decay = 1.f / (1.f + __expf(-decay_logits[h]));
  const float alpha = 1.f / (1.f + __expf(-iter_mix[0]));
  __shared__ float sd[64 * 193];
  const size_t base = (size_t)(b * 16 + h) * 1024 * 6;
  for (int it = 0; it < 96; ++it) {
    const int idx = it * 64 + lane;
    const int t = idx / 6, i = idx - 6 * t;
    const int ld = t >> 4, s = t & 15;
    sd[ld * 193 + s * 6 + i] = jwv[base + idx];
    sd[ld * 193 + 96 + s * 6 + i] = rdv[base + idx];
  }
  __syncthreads();
  const float* seg = sd + lane * 193;

  float C[21];
#pragma unroll
  for (int e = 0; e < 21; ++e) C[e] = 0.f;
  for (int s = 0; s < 16; ++s) {
    float J[6], dJ[6];
#pragma unroll
    for (int i = 0; i < 6; ++i) { J[i] = seg[s * 6 + i]; dJ[i] = decay * J[i]; }
#pragma unroll
    for (int i = 0; i < 6; ++i)
#pragma unroll
      for (int j = i; j < 6; ++j)
        C[midx(i, j)] = decay * C[midx(i, j)] + dJ[i] * J[j];
  }
  const float d2 = decay * decay, d4 = d2 * d2, d8 = d4 * d4;
  float fk = d8 * d8;  // d^16
#pragma unroll
  for (int k = 0; k < 6; ++k) {
    const int off = 1 << k;
#pragma unroll
    for (int e = 0; e < 21; ++e) {
      const float u = __shfl(C[e], lane - off);
      if (lane >= off) C[e] += fk * u;
    }
    fk = fk * fk;
  }
  float M[21];
#pragma unroll
  for (int e = 0; e < 21; ++e) {
    const float u = __shfl(C[e], lane - 1);
    M[e] = (lane >= 1) ? u : 0.f;
  }
  float* msp = mem_score + (size_t)(b * 16 + h) * 1024 + lane * 16;
  for (int s = 0; s < 16; ++s) {
    float J[6], r[6];
#pragma unroll
    for (int i = 0; i < 6; ++i) { J[i] = seg[s * 6 + i]; r[i] = seg[96 + s * 6 + i]; }
    float rdM[6];
#pragma unroll
    for (int i = 0; i < 6; ++i) {
      float a = 0.f;
#pragma unroll
      for (int j = 0; j < 6; ++j) a += M[midx(i, j)] * r[j];
      rdM[i] = a;
    }
    float s1 = 0.f, s2 = 0.f;
#pragma unroll
    for (int i = 0; i < 6; ++i) { s1 += rdM[i] * r[i]; s2 += rdM[i] * rdM[i]; }
    msp[s] = (1.f - alpha) * s1 + alpha * s2;
    float dJ[6];
#pragma unroll
    for (int i = 0; i < 6; ++i) dJ[i] = decay * J[i];
#pragma unroll
    for (int i = 0; i < 6; ++i)
#pragma unroll
      for (int j = i; j < 6; ++j)
        M[midx(i, j)] = decay * M[midx(i, j)] + dJ[i] * J[j];
  }
}

// ============ combine (fused gated-mean): attnin = seq + gm*mv  (f16 out) ============
__global__ __launch_bounds__(256) void combine_kernel(const _Float16* __restrict__ seq,
    const _Float16* __restrict__ mega, const float* __restrict__ ms,
    const float* __restrict__ gate, const float* __restrict__ mem_scale,
    _Float16* __restrict__ outp) {
  const int bt = blockIdx.x;
  const int b = bt >> 10, t = bt & 1023;
  __shared__ float hterm[16];
  const int tid = threadIdx.x;
  if (tid < 16) {
    const float sc = ms[(size_t)(b * 16 + tid) * 1024 + t];
    const float gt = gate[(size_t)bt * 16 + tid];
    hterm[tid] = (1.f / (1.f + __expf(-sc * mem_scale[tid]))) * gt;
  }
  __syncthreads();
  float acc = 0.f;
#pragma unroll
  for (int h = 0; h < 16; ++h) acc += hterm[h];
  const float g = acc * (1.f / 16.f);
  const f16x4 s4 = *(const f16x4*)(seq + (size_t)bt * 1024 + tid * 4);
  const f16x4 m4 = *(const f16x4*)(mega + (size_t)bt * QS + 3584 + tid * 4);
  f16x4 o;
#pragma unroll
  for (int j = 0; j < 4; ++j) o[j] = (_Float16)((float)s4[j] + g * (float)m4[j]);
  *(f16x4*)(outp + (size_t)bt * 1024 + tid * 4) = o;
}

// ============ dst = src + bias  (pre-init for atomic split-K GEMMs) ============
__global__ void addb_init(const float* __restrict__ src, const float* __restrict__ bias,
                          float* __restrict__ dst) {
  const size_t i = (size_t)blockIdx.x * 256 + threadIdx.x;
  const int c4 = (int)(i & 255);
  const float4 s = ((const float4*)src)[i];
  const float4 b = ((const float4*)bias)[c4];
  float4 o;
  o.x = s.x + b.x; o.y = s.y + b.y; o.z = s.z + b.z; o.w = s.w + b.w;
  ((float4*)dst)[i] = o;
}

extern "C" void kernel_launch(void* const* d_in, const int* in_sizes, int n_in,
                              void* d_out, int out_size, void* d_ws, size_t ws_size,
                              hipStream_t stream) {
  (void)in_sizes; (void)n_in; (void)out_size; (void)ws_size;
  const float* x       = (const float*)d_in[0];
  const float* ln1_g   = (const float*)d_in[1];
  const float* ln1_b   = (const float*)d_in[2];
  const float* Wqkv    = (const float*)d_in[3];
  const float* bqkv    = (const float*)d_in[4];
  const float* W1w     = (const float*)d_in[5];
  const float* W2w     = (const float*)d_in[6];
  const float* W1r     = (const float*)d_in[7];
  const float* W2r     = (const float*)d_in[8];
  const float* Wmv     = (const float*)d_in[9];
  const float* bmv     = (const float*)d_in[10];
  const float* Wmg     = (const float*)d_in[11];
  const float* bmg     = (const float*)d_in[12];
  const float* mscale  = (const float*)d_in[13];
  const float* itermix = (const float*)d_in[14];
  const float* dlogits = (const float*)d_in[15];
  const float* Wout    = (const float*)d_in[16];
  const float* bout    = (const float*)d_in[17];
  const float* ln2_g   = (const float*)d_in[18];
  const float* ln2_b   = (const float*)d_in[19];
  const float* Wfc     = (const float*)d_in[20];
  const float* bfc     = (const float*)d_in[21];
  const float* Wproj   = (const float*)d_in[22];
  const float* bproj   = (const float*)d_in[23];
  float* out = (float*)d_out;
  float* ws = (float*)d_ws;

  const size_t M1 = 1u << 20;
  _Float16* h16    = (_Float16*)ws;                         // 0 .. 1M1 (2M f16)
  _Float16* WmT    = (_Float16*)(ws + 1 * M1);              // 1M1 .. 3.25M1
  float*    bm     = ws + 3407872;                          // 3.25M1, 4608
  float*    jw     = ws + 3538944;                          // 196608
  float*    rd     = ws + 3538944 + 196608;
  float*    gate   = ws + 3538944 + 393216;                 // 32768
  float*    ms     = ws + 3538944 + 425984;                 // 32768
  float*    y      = ws + 4 * M1;                           // 4M1 .. 6M1
  _Float16* mega   = (_Float16*)(ws + 6 * M1);              // 6M1 .. 10.5M1 (2048x4608 f16)
  _Float16* fc16   = (_Float16*)(ws + 6 * M1);              // reuses mega (dead by then)
  _Float16* seq16  = (_Float16*)(ws + 11010048);            // 10.5M1 .. 11.5M1
  _Float16* WoutT  = (_Float16*)(ws + 12058624);            // 11.5M1 .. 12M1
  _Float16* WfcT   = (_Float16*)(ws + 12 * M1);             // 12M1 .. 14M1
  _Float16* WprojT = (_Float16*)(ws + 14 * M1);             // 14M1 .. 16M1

  // ---- fused weight prep (1 dispatch) ----
  prep_all<<<3474, 256, 0, stream>>>(Wqkv, W1w, W2w, W1r, W2r, Wmg, Wmv, Wout, Wfc, Wproj,
                                     bqkv, bmg, bmv, WmT, WoutT, WfcT, WprojT, bm);

  // ---- block ----
  ln16<<<2048, 256, 0, stream>>>(x, ln1_g, ln1_b, h16);
  gemm_t16<<<576, 512, 0, stream>>>(h16, WmT, bm, nullptr, mega, 4608, 1024, 0, 36, 1, 32);
  attn_mfma<<<dim3(8, 16, 2), 256, 0, stream>>>(mega, seq16);
  lines_post<<<128, 256, 0, stream>>>(mega, jw, rd, gate);
  gram_scan<<<32, 64, 0, stream>>>(jw, rd, dlogits, itermix, ms);
  combine_kernel<<<2048, 256, 0, stream>>>(seq16, mega, ms, gate, mscale, h16);
  // y = attnin @ Wout + bout + x   (direct mode 3, no split-K, no pre-init)
  gemm_t16<<<128, 512, 0, stream>>>(h16, WoutT, bout, x, y, 1024, 1024, 0, 8, 3, 32);
  ln16<<<2048, 256, 0, stream>>>(y, ln2_g, ln2_b, h16);
  // fc = gelu(h2 @ Wfc + bfc), stored f16 (overwrites mega)
  gemm_t16<<<512, 512, 0, stream>>>(h16, WfcT, bfc, nullptr, fc16, 4096, 1024, 1, 32, 1, 32);
  // out = y + bproj + fc @ Wproj   (split-K=4 atomics into pre-initialized out)
  addb_init<<<2048, 256, 0, stream>>>(y, bproj, out);
  gemm_t16<<<dim3(128, 4), 512, 0, stream>>>(fc16, WprojT, nullptr, nullptr, out, 1024, 4096, 0, 8, 2, 32);
}